// Round 3
// baseline (405.884 us; speedup 1.0000x reference)
//
#include <hip/hip_runtime.h>
#include <hip/hip_bf16.h>

using bf16 = __hip_bfloat16;
typedef __attribute__((ext_vector_type(8))) __bf16 bf16x8;
typedef __attribute__((ext_vector_type(4))) float f32x4;

#define MFMA16(a, b, c) __builtin_amdgcn_mfma_f32_16x16x32_bf16((a), (b), (c), 0, 0, 0)

static __device__ __forceinline__ void gload_lds16(const bf16* g, bf16* l) {
    __builtin_amdgcn_global_load_lds(
        (__attribute__((address_space(1))) void*)(bf16*)(g),
        (__attribute__((address_space(3))) void*)(l), 16, 0, 0);
}

// ---------------------------------------------------------------- convert
__global__ void cvt_f32_bf16(const float* __restrict__ in, bf16* __restrict__ out, int n4) {
    int i = blockIdx.x * 256 + threadIdx.x;
    if (i >= n4) return;
    float4 v = ((const float4*)in)[i];
    bf16 t[4];
    t[0] = __float2bfloat16(v.x);
    t[1] = __float2bfloat16(v.y);
    t[2] = __float2bfloat16(v.z);
    t[3] = __float2bfloat16(v.w);
    *(uint2*)(out + 4l * i) = *(uint2*)t;
}

// ---------------------------------------------------------------- GEMM1: qkv = x @ Wqkv^T + b, scatter to Q,K,V^T (bf16)
__global__ void gemm_qkv(const bf16* __restrict__ A, const bf16* __restrict__ B,
                         const float* __restrict__ bias,
                         bf16* __restrict__ Qo, bf16* __restrict__ Ko, bf16* __restrict__ Vt) {
    const int K = 1024;
    __shared__ bf16 Alds[128 * 32];
    __shared__ bf16 Blds[128 * 32];
    int t = threadIdx.x;
    int lane = t & 63;
    int wave = t >> 6;
    int wm = wave >> 1, wn = wave & 1;
    int r = lane & 15, q = lane >> 4;
    long m0 = (long)blockIdx.y * 128;
    long n0 = (long)blockIdx.x * 128;
    const bf16* Ab = A + m0 * K;
    const bf16* Bb = B + n0 * K;

    f32x4 acc[4][4] = {};

    int srow = t >> 2;
    int scol = (t & 3) << 3;

    for (int k0 = 0; k0 < K; k0 += 32) {
        __syncthreads();
        gload_lds16(Ab + (long)srow * K + k0 + scol, Alds + t * 8);
        gload_lds16(Ab + (long)(srow + 64) * K + k0 + scol, Alds + 2048 + t * 8);
        gload_lds16(Bb + (long)srow * K + k0 + scol, Blds + t * 8);
        gload_lds16(Bb + (long)(srow + 64) * K + k0 + scol, Blds + 2048 + t * 8);
        __syncthreads();

        bf16x8 af[4], bfv[4];
#pragma unroll
        for (int mi = 0; mi < 4; mi++)
            af[mi] = *(const bf16x8*)(Alds + (wm * 64 + mi * 16 + r) * 32 + q * 8);
#pragma unroll
        for (int ni = 0; ni < 4; ni++)
            bfv[ni] = *(const bf16x8*)(Blds + (wn * 64 + ni * 16 + r) * 32 + q * 8);
#pragma unroll
        for (int mi = 0; mi < 4; mi++)
#pragma unroll
            for (int ni = 0; ni < 4; ni++)
                acc[mi][ni] = MFMA16(af[mi], bfv[ni], acc[mi][ni]);
    }

#pragma unroll
    for (int ni = 0; ni < 4; ni++) {
        int n = (int)n0 + wn * 64 + ni * 16 + r;
        float bn = bias[n];
        int h = n / 192;
        int rem = n % 192;
        int part = rem >> 6;
        int d = rem & 63;
#pragma unroll
        for (int mi = 0; mi < 4; mi++) {
#pragma unroll
            for (int rr = 0; rr < 4; rr++) {
                int m = (int)m0 + wm * 64 + mi * 16 + q * 4 + rr;
                int b = m >> 11;
                int row = m & 2047;
                long bh = b * 16 + h;
                bf16 bv = __float2bfloat16(acc[mi][ni][rr] + bn);
                if (part == 0)      Qo[(bh * 2048 + row) * 64 + d] = bv;
                else if (part == 1) Ko[(bh * 2048 + row) * 64 + d] = bv;
                else                Vt[(bh * 64 + d) * 2048 + row] = bv;
            }
        }
    }
}

// ---------------------------------------------------------------- attention (flash, swapped-QK^T lane-local softmax)
// Q,K: [BH][2048][64] bf16 ; Vt: [BH][64][2048] bf16 ; AO: [B][2048][1024] bf16
// Block: 4 waves x 32 q-rows = 128 q-rows; KVBLK=64.
__global__ void attn_fwd(const bf16* __restrict__ Q, const bf16* __restrict__ Kg,
                         const bf16* __restrict__ Vt, bf16* __restrict__ AO) {
    __shared__ bf16 Klds[64 * 64];       // [kv][d], 16B-block XOR swizzle on d
    __shared__ bf16 Vlds[64 * 64];       // [d][kv], 16B-block XOR swizzle on kv
    __shared__ bf16 Plds[4][32 * 64];    // per-wave [qrow 32][kv 64], swizzled
    int t = threadIdx.x, lane = t & 63, wave = t >> 6;
    int r = lane & 15, c4 = lane >> 4;
    int qt = blockIdx.x, bh = blockIdx.y;
    const float C1 = 0.18033688011112042f;  // log2(e) / sqrt(64)

    // Q fragments held in registers for the whole kernel (2 qsets x 2 d-halves)
    const bf16* Qh = Q + ((long)bh * 2048 + qt * 128 + wave * 32) * 64;
    bf16x8 qf[2][2];
#pragma unroll
    for (int qs = 0; qs < 2; ++qs) {
        qf[qs][0] = *(const bf16x8*)(Qh + (qs * 16 + r) * 64 + c4 * 8);
        qf[qs][1] = *(const bf16x8*)(Qh + (qs * 16 + r) * 64 + 32 + c4 * 8);
    }

    const bf16* Kh = Kg + (long)bh * 2048 * 64;
    const bf16* Vh = Vt + (long)bh * 64 * 2048;
    bf16* Pw = Plds[wave];

    f32x4 acc[2][4] = {};
    float mrow[2] = {-1e30f, -1e30f};
    float lrow[2] = {0.f, 0.f};

    // async-split staging state (4x int4 per thread in flight)
    int4 kr[2], vr[2];
    int srow[2], sblk[2];
#pragma unroll
    for (int c = 0; c < 2; ++c) {
        int idx = c * 256 + t;
        srow[c] = idx >> 3;
        sblk[c] = idx & 7;
    }
    auto load_tile = [&](int kv0) {
#pragma unroll
        for (int c = 0; c < 2; ++c) {
            int idx = c * 256 + t;
            kr[c] = *(const int4*)(Kh + (long)kv0 * 64 + idx * 8);
            vr[c] = *(const int4*)(Vh + (long)srow[c] * 2048 + kv0 + sblk[c] * 8);
        }
    };
    auto write_tile = [&]() {
#pragma unroll
        for (int c = 0; c < 2; ++c) {
            int sb = sblk[c] ^ (srow[c] & 7);
            *(int4*)(Klds + srow[c] * 64 + sb * 8) = kr[c];
            *(int4*)(Vlds + srow[c] * 64 + sb * 8) = vr[c];
        }
    };

    load_tile(0);
    write_tile();
    load_tile(64);
    __syncthreads();

    for (int kv0 = 0;; kv0 += 64) {
        // ---- S^T = K Q^T via swapped MFMA: lane holds s for q-row (qs*16 + r), kv = g*16 + c4*4 + reg
        f32x4 sArr[2][4];
#pragma unroll
        for (int g = 0; g < 4; ++g) {
            int krow = g * 16 + r;
            int sw = krow & 7;
            bf16x8 kf0 = *(const bf16x8*)(Klds + krow * 64 + ((c4 ^ sw) << 3));
            bf16x8 kf1 = *(const bf16x8*)(Klds + krow * 64 + (((4 + c4) ^ sw) << 3));
#pragma unroll
            for (int qs = 0; qs < 2; ++qs) {
                f32x4 z = {0.f, 0.f, 0.f, 0.f};
                z = MFMA16(kf0, qf[qs][0], z);
                z = MFMA16(kf1, qf[qs][1], z);
                sArr[qs][g] = z;
            }
        }

        // ---- softmax: row-local within 4-lane group {r, r+16, r+32, r+48}
        float alv[2];
#pragma unroll
        for (int qs = 0; qs < 2; ++qs) {
            float tmax = sArr[qs][0][0];
#pragma unroll
            for (int g = 0; g < 4; ++g)
#pragma unroll
                for (int e = 0; e < 4; ++e) tmax = fmaxf(tmax, sArr[qs][g][e]);
            tmax = fmaxf(tmax, __shfl_xor(tmax, 16));
            tmax = fmaxf(tmax, __shfl_xor(tmax, 32));
            float mn = fmaxf(mrow[qs], tmax);
            float al = exp2f((mrow[qs] - mn) * C1);
            mrow[qs] = mn;
            float mnC = mn * C1;
            float tsum = 0.f;
            int pr = qs * 16 + r;
            int psw = pr & 7;
#pragma unroll
            for (int g = 0; g < 4; ++g) {
                union { bf16 h[4]; uint2 u; } pk;
#pragma unroll
                for (int e = 0; e < 4; ++e) {
                    float pv = exp2f(sArr[qs][g][e] * C1 - mnC);
                    tsum += pv;
                    pk.h[e] = __float2bfloat16(pv);
                }
                int bidx = 2 * g + (c4 >> 1);
                *(uint2*)(Pw + pr * 64 + (((bidx ^ psw) << 3) | ((c4 & 1) << 2))) = pk.u;
            }
            tsum += __shfl_xor(tsum, 16);
            tsum += __shfl_xor(tsum, 32);
            lrow[qs] = lrow[qs] * al + tsum;
            alv[qs] = al;
        }

        // ---- rescale acc: pull al for rows c4*4+rr
#pragma unroll
        for (int rr = 0; rr < 4; ++rr) {
            int src = c4 * 4 + rr;
            float a0 = __shfl(alv[0], src);
            float a1 = __shfl(alv[1], src);
#pragma unroll
            for (int dg = 0; dg < 4; ++dg) {
                acc[0][dg][rr] *= a0;
                acc[1][dg][rr] *= a1;
            }
        }

        // ---- O += P V
        bf16x8 pf[2][2];
#pragma unroll
        for (int qs = 0; qs < 2; ++qs) {
            int pr = qs * 16 + r;
            int psw = pr & 7;
            pf[qs][0] = *(const bf16x8*)(Pw + pr * 64 + ((c4 ^ psw) << 3));
            pf[qs][1] = *(const bf16x8*)(Pw + pr * 64 + (((4 + c4) ^ psw) << 3));
        }
#pragma unroll
        for (int dg = 0; dg < 4; ++dg) {
            int vrow = dg * 16 + r;
            int sw = vrow & 7;
            bf16x8 vf0 = *(const bf16x8*)(Vlds + vrow * 64 + ((c4 ^ sw) << 3));
            bf16x8 vf1 = *(const bf16x8*)(Vlds + vrow * 64 + (((4 + c4) ^ sw) << 3));
#pragma unroll
            for (int qs = 0; qs < 2; ++qs) {
                acc[qs][dg] = MFMA16(pf[qs][0], vf0, acc[qs][dg]);
                acc[qs][dg] = MFMA16(pf[qs][1], vf1, acc[qs][dg]);
            }
        }

        if (kv0 == 2048 - 64) break;
        __syncthreads();
        write_tile();  // compiler inserts vmcnt wait on kr/vr
        int nxt = kv0 + 128;
        if (nxt > 2048 - 64) nxt = 2048 - 64;
        load_tile(nxt);
        __syncthreads();
    }

    // ---- epilogue: O row = qt*128 + wave*32 + qs*16 + c4*4 + rr, col = dg*16 + r
    long b = bh >> 4;
    long h = bh & 15;
    float il[2][4];
#pragma unroll
    for (int rr = 0; rr < 4; ++rr) {
        int src = c4 * 4 + rr;
        il[0][rr] = 1.f / __shfl(lrow[0], src);
        il[1][rr] = 1.f / __shfl(lrow[1], src);
    }
#pragma unroll
    for (int qs = 0; qs < 2; ++qs) {
#pragma unroll
        for (int dg = 0; dg < 4; ++dg) {
#pragma unroll
            for (int rr = 0; rr < 4; ++rr) {
                long qrow = (long)qt * 128 + wave * 32 + qs * 16 + c4 * 4 + rr;
                float o = acc[qs][dg][rr] * il[qs][rr];
                AO[(b * 2048 + qrow) * 1024 + h * 64 + dg * 16 + r] = __float2bfloat16(o);
            }
        }
    }
}

// ---------------------------------------------------------------- GEMM2: out = AO @ Wo^T + bo (fp32 out)
__global__ void gemm_out(const bf16* __restrict__ A, const bf16* __restrict__ B,
                         const float* __restrict__ bias, float* __restrict__ C) {
    const int K = 1024, N = 1024;
    __shared__ bf16 Alds[128 * 32];
    __shared__ bf16 Blds[128 * 32];
    int t = threadIdx.x;
    int lane = t & 63;
    int wave = t >> 6;
    int wm = wave >> 1, wn = wave & 1;
    int r = lane & 15, q = lane >> 4;
    long m0 = (long)blockIdx.y * 128;
    long n0 = (long)blockIdx.x * 128;
    const bf16* Ab = A + m0 * K;
    const bf16* Bb = B + n0 * K;

    f32x4 acc[4][4] = {};

    int srow = t >> 2;
    int scol = (t & 3) << 3;

    for (int k0 = 0; k0 < K; k0 += 32) {
        __syncthreads();
        gload_lds16(Ab + (long)srow * K + k0 + scol, Alds + t * 8);
        gload_lds16(Ab + (long)(srow + 64) * K + k0 + scol, Alds + 2048 + t * 8);
        gload_lds16(Bb + (long)srow * K + k0 + scol, Blds + t * 8);
        gload_lds16(Bb + (long)(srow + 64) * K + k0 + scol, Blds + 2048 + t * 8);
        __syncthreads();

        bf16x8 af[4], bfv[4];
#pragma unroll
        for (int mi = 0; mi < 4; mi++)
            af[mi] = *(const bf16x8*)(Alds + (wm * 64 + mi * 16 + r) * 32 + q * 8);
#pragma unroll
        for (int ni = 0; ni < 4; ni++)
            bfv[ni] = *(const bf16x8*)(Blds + (wn * 64 + ni * 16 + r) * 32 + q * 8);
#pragma unroll
        for (int mi = 0; mi < 4; mi++)
#pragma unroll
            for (int ni = 0; ni < 4; ni++)
                acc[mi][ni] = MFMA16(af[mi], bfv[ni], acc[mi][ni]);
    }

#pragma unroll
    for (int ni = 0; ni < 4; ni++) {
        int n = (int)n0 + wn * 64 + ni * 16 + r;
        float bn = bias[n];
#pragma unroll
        for (int mi = 0; mi < 4; mi++) {
#pragma unroll
            for (int rr = 0; rr < 4; rr++) {
                long m = m0 + wm * 64 + mi * 16 + q * 4 + rr;
                C[m * N + n] = acc[mi][ni][rr] + bn;
            }
        }
    }
}

// ---------------------------------------------------------------- launch
extern "C" void kernel_launch(void* const* d_in, const int* in_sizes, int n_in,
                              void* d_out, int out_size, void* d_ws, size_t ws_size,
                              hipStream_t stream) {
    const float* x    = (const float*)d_in[0];
    const float* Wqkv = (const float*)d_in[1];
    const float* bqkv = (const float*)d_in[2];
    const float* Wo   = (const float*)d_in[3];
    const float* bo   = (const float*)d_in[4];
    float* out = (float*)d_out;

    char* ws = (char*)d_ws;
    bf16* Xb  = (bf16*)(ws + 0);
    bf16* Wqb = (bf16*)(ws + 16777216);
    bf16* Wob = (bf16*)(ws + 23068672);
    bf16* Qb  = (bf16*)(ws + 25165824);
    bf16* Kb  = (bf16*)(ws + 41943040);
    bf16* Vtb = (bf16*)(ws + 58720256);
    bf16* AOb = (bf16*)(ws + 75497472);

    cvt_f32_bf16<<<8192, 256, 0, stream>>>(x, Xb, 8192 * 1024 / 4);
    cvt_f32_bf16<<<3072, 256, 0, stream>>>(Wqkv, Wqb, 3072 * 1024 / 4);
    cvt_f32_bf16<<<1024, 256, 0, stream>>>(Wo, Wob, 1024 * 1024 / 4);

    gemm_qkv<<<dim3(24, 64), 256, 0, stream>>>(Xb, Wqb, bqkv, Qb, Kb, Vtb);
    attn_fwd<<<dim3(16, 64), 256, 0, stream>>>(Qb, Kb, Vtb, AOb);
    gemm_out<<<dim3(8, 64), 256, 0, stream>>>(AOb, Wob, bo, out);
}

// Round 4
// 270.972 us; speedup vs baseline: 1.4979x; 1.4979x over previous
//
#include <hip/hip_runtime.h>
#include <hip/hip_bf16.h>

using bf16 = __hip_bfloat16;
typedef __attribute__((ext_vector_type(8))) __bf16 bf16x8;
typedef __attribute__((ext_vector_type(4))) float f32x4;
typedef __attribute__((ext_vector_type(16))) float f32x16;

#define MFMA16(a, b, c) __builtin_amdgcn_mfma_f32_16x16x32_bf16((a), (b), (c), 0, 0, 0)
#define MFMA32(a, b, c) __builtin_amdgcn_mfma_f32_32x32x16_bf16((a), (b), (c), 0, 0, 0)

static __device__ __forceinline__ void gload_lds16(const bf16* g, bf16* l) {
    __builtin_amdgcn_global_load_lds(
        (__attribute__((address_space(1))) void*)(bf16*)(g),
        (__attribute__((address_space(3))) void*)(l), 16, 0, 0);
}

static __device__ __forceinline__ unsigned cvtpk(float lo, float hi) {
    unsigned r;
    asm("v_cvt_pk_bf16_f32 %0, %1, %2" : "=v"(r) : "v"(lo), "v"(hi));
    return r;
}

// ---------------------------------------------------------------- convert
__global__ void cvt_f32_bf16(const float* __restrict__ in, bf16* __restrict__ out, int n4) {
    int i = blockIdx.x * 256 + threadIdx.x;
    if (i >= n4) return;
    float4 v = ((const float4*)in)[i];
    bf16 t[4];
    t[0] = __float2bfloat16(v.x);
    t[1] = __float2bfloat16(v.y);
    t[2] = __float2bfloat16(v.z);
    t[3] = __float2bfloat16(v.w);
    *(uint2*)(out + 4l * i) = *(uint2*)t;
}

// ---------------------------------------------------------------- GEMM1: qkv = x @ Wqkv^T + b, scatter to Q,K,V^T (bf16)
__global__ void gemm_qkv(const bf16* __restrict__ A, const bf16* __restrict__ B,
                         const float* __restrict__ bias,
                         bf16* __restrict__ Qo, bf16* __restrict__ Ko, bf16* __restrict__ Vt) {
    const int K = 1024;
    __shared__ bf16 Alds[128 * 32];
    __shared__ bf16 Blds[128 * 32];
    int t = threadIdx.x;
    int lane = t & 63;
    int wave = t >> 6;
    int wm = wave >> 1, wn = wave & 1;
    int r = lane & 15, q = lane >> 4;
    long m0 = (long)blockIdx.y * 128;
    long n0 = (long)blockIdx.x * 128;
    const bf16* Ab = A + m0 * K;
    const bf16* Bb = B + n0 * K;

    f32x4 acc[4][4] = {};

    int srow = t >> 2;
    int scol = (t & 3) << 3;

    for (int k0 = 0; k0 < K; k0 += 32) {
        __syncthreads();
        gload_lds16(Ab + (long)srow * K + k0 + scol, Alds + t * 8);
        gload_lds16(Ab + (long)(srow + 64) * K + k0 + scol, Alds + 2048 + t * 8);
        gload_lds16(Bb + (long)srow * K + k0 + scol, Blds + t * 8);
        gload_lds16(Bb + (long)(srow + 64) * K + k0 + scol, Blds + 2048 + t * 8);
        __syncthreads();

        bf16x8 af[4], bfv[4];
#pragma unroll
        for (int mi = 0; mi < 4; mi++)
            af[mi] = *(const bf16x8*)(Alds + (wm * 64 + mi * 16 + r) * 32 + q * 8);
#pragma unroll
        for (int ni = 0; ni < 4; ni++)
            bfv[ni] = *(const bf16x8*)(Blds + (wn * 64 + ni * 16 + r) * 32 + q * 8);
#pragma unroll
        for (int mi = 0; mi < 4; mi++)
#pragma unroll
            for (int ni = 0; ni < 4; ni++)
                acc[mi][ni] = MFMA16(af[mi], bfv[ni], acc[mi][ni]);
    }

#pragma unroll
    for (int ni = 0; ni < 4; ni++) {
        int n = (int)n0 + wn * 64 + ni * 16 + r;
        float bn = bias[n];
        int h = n / 192;
        int rem = n % 192;
        int part = rem >> 6;
        int d = rem & 63;
#pragma unroll
        for (int mi = 0; mi < 4; mi++) {
#pragma unroll
            for (int rr = 0; rr < 4; rr++) {
                int m = (int)m0 + wm * 64 + mi * 16 + q * 4 + rr;
                int b = m >> 11;
                int row = m & 2047;
                long bh = b * 16 + h;
                bf16 bv = __float2bfloat16(acc[mi][ni][rr] + bn);
                if (part == 0)      Qo[(bh * 2048 + row) * 64 + d] = bv;
                else if (part == 1) Ko[(bh * 2048 + row) * 64 + d] = bv;
                else                Vt[(bh * 64 + d) * 2048 + row] = bv;
            }
        }
    }
}

// ---------------------------------------------------------------- attention
// 32x32 MFMA, swapped QK^T (S^T), in-register P, O^T accumulation.
// Q,K: [BH][2048][64] ; Vt: [BH][64][2048] ; AO: [B][2048][1024]
// Block: 4 waves x 64 q-rows = 256 q; KVBLK = 64; frag-linear LDS (no conflicts).
union PU { unsigned u[4]; bf16x8 v; };

#define PACK8(S, OFF, F) { \
    unsigned A0 = cvtpk(S[OFF+0], S[OFF+1]); \
    unsigned B0 = cvtpk(S[OFF+4], S[OFF+5]); \
    unsigned A1 = cvtpk(S[OFF+2], S[OFF+3]); \
    unsigned B1 = cvtpk(S[OFF+6], S[OFF+7]); \
    unsigned snd0 = hi ? A0 : B0; unsigned got0 = (unsigned)__shfl_xor((int)snd0, 32); \
    unsigned snd1 = hi ? A1 : B1; unsigned got1 = (unsigned)__shfl_xor((int)snd1, 32); \
    F.u[0] = hi ? got0 : A0; F.u[2] = hi ? B0 : got0; \
    F.u[1] = hi ? got1 : A1; F.u[3] = hi ? B1 : got1; }

#define QB_PROC(sA, sB, o0, o1, m, l) do { \
    float pm = sA[0]; \
    _Pragma("unroll") for (int e = 1; e < 16; ++e) pm = fmaxf(pm, sA[e]); \
    _Pragma("unroll") for (int e = 0; e < 16; ++e) pm = fmaxf(pm, sB[e]); \
    pm = fmaxf(pm, __shfl_xor(pm, 32)); \
    float mn = fmaxf(m, pm); \
    float al = exp2f((m - mn) * C1); \
    m = mn; float mc = mn * C1; float ts = 0.f; \
    _Pragma("unroll") for (int e = 0; e < 16; ++e) { float p = exp2f(sA[e] * C1 - mc); sA[e] = p; ts += p; } \
    _Pragma("unroll") for (int e = 0; e < 16; ++e) { float p = exp2f(sB[e] * C1 - mc); sB[e] = p; ts += p; } \
    ts += __shfl_xor(ts, 32); \
    l = l * al + ts; \
    _Pragma("unroll") for (int e = 0; e < 16; ++e) { o0[e] *= al; o1[e] *= al; } \
    PU f0, f1, f2, f3; \
    PACK8(sA, 0, f0); PACK8(sA, 8, f1); PACK8(sB, 0, f2); PACK8(sB, 8, f3); \
    o0 = MFMA32(vf[0][0], f0.v, o0); o1 = MFMA32(vf[1][0], f0.v, o1); \
    o0 = MFMA32(vf[0][1], f1.v, o0); o1 = MFMA32(vf[1][1], f1.v, o1); \
    o0 = MFMA32(vf[0][2], f2.v, o0); o1 = MFMA32(vf[1][2], f2.v, o1); \
    o0 = MFMA32(vf[0][3], f3.v, o0); o1 = MFMA32(vf[1][3], f3.v, o1); \
} while (0)

__global__ __launch_bounds__(256, 2) void attn_fwd(const bf16* __restrict__ Q,
                                                   const bf16* __restrict__ Kg,
                                                   const bf16* __restrict__ Vt,
                                                   bf16* __restrict__ AO) {
    __shared__ bf16 smem[8192];   // K frags [0..4095], V frags [4096..8191]
    bf16* Ksh = smem;
    bf16* Vsh = smem + 4096;
    const int t = threadIdx.x;
    const int lane = t & 63, wave = t >> 6;
    const int l31 = lane & 31, hi = lane >> 5;
    const int qt = blockIdx.x, bh = blockIdx.y;
    const float C1 = 0.18033688011112042f;   // log2(e)/sqrt(64)

    // Q fragments, held in registers all kernel: qf[qb][k0]
    bf16x8 qf[2][4];
    {
        const bf16* Qb = Q + ((long)bh * 2048 + qt * 256 + wave * 64 + l31) * 64 + hi * 8;
#pragma unroll
        for (int qb = 0; qb < 2; ++qb)
#pragma unroll
            for (int k0 = 0; k0 < 4; ++k0)
                qf[qb][k0] = *(const bf16x8*)(Qb + (long)qb * 32 * 64 + k0 * 16);
    }

    const bf16* Kh = Kg + (long)bh * 2048 * 64;
    const bf16* Vh = Vt + (long)bh * 64 * 2048;

    // O^T accumulators: o<ds><qb>, m/l per qb (lane-local: q = l31)
    f32x16 o00 = {}, o01 = {}, o10 = {}, o11 = {};
    float m0v = -1e30f, m1v = -1e30f, l0v = 0.f, l1v = 0.f;

    // async staging: regs hold next tile (frag-linear slots: slot = c*256 + t)
    int4 kr[2], vr[2];
    auto stage_load = [&](int kv0) {
#pragma unroll
        for (int c = 0; c < 2; ++c) {
            kr[c] = *(const int4*)(Kh + (long)(kv0 + c * 32 + l31) * 64 + wave * 16 + hi * 8);
            vr[c] = *(const int4*)(Vh + (long)(c * 32 + l31) * 2048 + kv0 + wave * 16 + hi * 8);
        }
    };
    auto stage_write = [&]() {
#pragma unroll
        for (int c = 0; c < 2; ++c) {
            *(int4*)(Ksh + ((c << 8) + t) * 8) = kr[c];
            *(int4*)(Vsh + ((c << 8) + t) * 8) = vr[c];
        }
    };

    stage_load(0);
    stage_write();
    stage_load(64);
    __syncthreads();

    for (int kv0 = 0;; kv0 += 64) {
        // ---- S^T = K·Q^T : 4 accs (qb x kvsub), K-frags read frag-linear (0 conflicts)
        f32x16 s00 = {}, s01 = {}, s10 = {}, s11 = {};
#pragma unroll
        for (int k0 = 0; k0 < 4; ++k0) {
            bf16x8 kfA = *(const bf16x8*)(Ksh + (k0 * 64 + lane) * 8);
            bf16x8 kfB = *(const bf16x8*)(Ksh + (256 + k0 * 64 + lane) * 8);
            s00 = MFMA32(kfA, qf[0][k0], s00);
            s10 = MFMA32(kfA, qf[1][k0], s10);
            s01 = MFMA32(kfB, qf[0][k0], s01);
            s11 = MFMA32(kfB, qf[1][k0], s11);
        }
        // ---- V frags (frag-linear, 0 conflicts)
        bf16x8 vf[2][4];
#pragma unroll
        for (int ds = 0; ds < 2; ++ds)
#pragma unroll
            for (int kf = 0; kf < 4; ++kf)
                vf[ds][kf] = *(const bf16x8*)(Vsh + (ds * 256 + kf * 64 + lane) * 8);

        // ---- softmax (lane-local) + in-register P + PV, per q-block
        QB_PROC(s00, s01, o00, o10, m0v, l0v);
        QB_PROC(s10, s11, o01, o11, m1v, l1v);

        if (kv0 == 2048 - 64) break;
        __syncthreads();
        stage_write();                       // tile kv0+64 from regs
        if (kv0 + 128 < 2048) stage_load(kv0 + 128);
        __syncthreads();
    }

    // ---- epilogue: O^T -> LDS transpose (per qb) -> coalesced global stores
    long b = bh >> 4, h = bh & 15;
#pragma unroll
    for (int qb = 0; qb < 2; ++qb) {
        __syncthreads();
        float il = 1.f / (qb ? l1v : l0v);
        char* wbase = (char*)smem + wave * 4096 + l31 * 128;
#pragma unroll
        for (int ds = 0; ds < 2; ++ds) {
            const f32x16& E = qb ? (ds ? o11 : o01) : (ds ? o10 : o00);
#pragma unroll
            for (int j = 0; j < 4; ++j) {
                unsigned wlo = cvtpk(E[4 * j] * il, E[4 * j + 1] * il);
                unsigned whi = cvtpk(E[4 * j + 2] * il, E[4 * j + 3] * il);
                int b8 = ds * 8 + 2 * j + hi;
                int b8s = b8 ^ ((l31 & 7) << 1);
                uint2 val; val.x = wlo; val.y = whi;
                *(uint2*)(wbase + b8s * 8) = val;
            }
        }
        __syncthreads();
        int rid = t >> 1, hf = t & 1;
        int wv = rid >> 5, qq = rid & 31;
        long orow = (long)qt * 256 + wv * 64 + qb * 32 + qq;
        const char* rbase = (const char*)smem + wv * 4096 + qq * 128;
        bf16* dst = AO + (b * 2048 + orow) * 1024 + h * 64 + hf * 32;
#pragma unroll
        for (int k = 0; k < 4; ++k) {
            int b8 = hf * 8 + 2 * k;
            int b8s = b8 ^ ((qq & 7) << 1);
            int4 v = *(const int4*)(rbase + b8s * 8);
            *(int4*)(dst + k * 8) = v;
        }
    }
}

// ---------------------------------------------------------------- GEMM2: out = AO @ Wo^T + bo (fp32 out)
__global__ void gemm_out(const bf16* __restrict__ A, const bf16* __restrict__ B,
                         const float* __restrict__ bias, float* __restrict__ C) {
    const int K = 1024, N = 1024;
    __shared__ bf16 Alds[128 * 32];
    __shared__ bf16 Blds[128 * 32];
    int t = threadIdx.x;
    int lane = t & 63;
    int wave = t >> 6;
    int wm = wave >> 1, wn = wave & 1;
    int r = lane & 15, q = lane >> 4;
    long m0 = (long)blockIdx.y * 128;
    long n0 = (long)blockIdx.x * 128;
    const bf16* Ab = A + m0 * K;
    const bf16* Bb = B + n0 * K;

    f32x4 acc[4][4] = {};

    int srow = t >> 2;
    int scol = (t & 3) << 3;

    for (int k0 = 0; k0 < K; k0 += 32) {
        __syncthreads();
        gload_lds16(Ab + (long)srow * K + k0 + scol, Alds + t * 8);
        gload_lds16(Ab + (long)(srow + 64) * K + k0 + scol, Alds + 2048 + t * 8);
        gload_lds16(Bb + (long)srow * K + k0 + scol, Blds + t * 8);
        gload_lds16(Bb + (long)(srow + 64) * K + k0 + scol, Blds + 2048 + t * 8);
        __syncthreads();

        bf16x8 af[4], bfv[4];
#pragma unroll
        for (int mi = 0; mi < 4; mi++)
            af[mi] = *(const bf16x8*)(Alds + (wm * 64 + mi * 16 + r) * 32 + q * 8);
#pragma unroll
        for (int ni = 0; ni < 4; ni++)
            bfv[ni] = *(const bf16x8*)(Blds + (wn * 64 + ni * 16 + r) * 32 + q * 8);
#pragma unroll
        for (int mi = 0; mi < 4; mi++)
#pragma unroll
            for (int ni = 0; ni < 4; ni++)
                acc[mi][ni] = MFMA16(af[mi], bfv[ni], acc[mi][ni]);
    }

#pragma unroll
    for (int ni = 0; ni < 4; ni++) {
        int n = (int)n0 + wn * 64 + ni * 16 + r;
        float bn = bias[n];
#pragma unroll
        for (int mi = 0; mi < 4; mi++) {
#pragma unroll
            for (int rr = 0; rr < 4; rr++) {
                long m = m0 + wm * 64 + mi * 16 + q * 4 + rr;
                C[m * N + n] = acc[mi][ni][rr] + bn;
            }
        }
    }
}

// ---------------------------------------------------------------- launch
extern "C" void kernel_launch(void* const* d_in, const int* in_sizes, int n_in,
                              void* d_out, int out_size, void* d_ws, size_t ws_size,
                              hipStream_t stream) {
    const float* x    = (const float*)d_in[0];
    const float* Wqkv = (const float*)d_in[1];
    const float* bqkv = (const float*)d_in[2];
    const float* Wo   = (const float*)d_in[3];
    const float* bo   = (const float*)d_in[4];
    float* out = (float*)d_out;

    char* ws = (char*)d_ws;
    bf16* Xb  = (bf16*)(ws + 0);
    bf16* Wqb = (bf16*)(ws + 16777216);
    bf16* Wob = (bf16*)(ws + 23068672);
    bf16* Qb  = (bf16*)(ws + 25165824);
    bf16* Kb  = (bf16*)(ws + 41943040);
    bf16* Vtb = (bf16*)(ws + 58720256);
    bf16* AOb = (bf16*)(ws + 75497472);

    cvt_f32_bf16<<<8192, 256, 0, stream>>>(x, Xb, 8192 * 1024 / 4);
    cvt_f32_bf16<<<3072, 256, 0, stream>>>(Wqkv, Wqb, 3072 * 1024 / 4);
    cvt_f32_bf16<<<1024, 256, 0, stream>>>(Wo, Wob, 1024 * 1024 / 4);

    gemm_qkv<<<dim3(24, 64), 256, 0, stream>>>(Xb, Wqb, bqkv, Qb, Kb, Vtb);
    attn_fwd<<<dim3(8, 64), 256, 0, stream>>>(Qb, Kb, Vtb, AOb);
    gemm_out<<<dim3(8, 64), 256, 0, stream>>>(AOb, Wob, bo, out);
}